// Round 1
// baseline (2158.387 us; speedup 1.0000x reference)
//
#include <hip/hip_runtime.h>

// LSTMDecoder: B=256, D=512, T=64, 2 layers. Persistent cooperative kernel.
// 256 WGs x 256 thr (1/CU). Weights fp16 in LDS (MFMA B-frag order), c-state in
// registers, h exchanged via fp16 double buffers in d_ws, per-b-group slot barrier.

#define B_DIM 256
#define D_DIM 512
#define T_N   64
#define BD    131072            // B*D
#define SMEM_WBYTES 131072      // 2 layers * 32 rows * 1024 K * 2B (frag order)
#define SMEM_BYTES  (SMEM_WBYTES + 4 * 1056 * 4)   // + red[4][32][33] f32

#define WS_SLOTS  0                       // 4 groups * 64 slots * 128B = 32768
#define WS_XINIT  32768
#define WS_H0B0   (WS_XINIT + BD * 2)
#define WS_H0B1   (WS_H0B0 + BD * 2)
#define WS_H1B0   (WS_H0B1 + BD * 2)
#define WS_H1B1   (WS_H1B0 + BD * 2)     // total ws = 1343488 B

typedef _Float16 half8_t  __attribute__((ext_vector_type(8)));
typedef float    f32x16_t __attribute__((ext_vector_type(16)));

__device__ __forceinline__ float sigmoidf_(float x) {
  float z = __expf(-fabsf(x));
  float s = 1.0f / (1.0f + z);
  return x >= 0.0f ? s : 1.0f - s;
}
__device__ __forceinline__ float tanhf_(float x) {   // overflow-safe tanh
  float z = __expf(-2.0f * fabsf(x));
  float t = (1.0f - z) / (1.0f + z);
  return x >= 0.0f ? t : -t;
}

__global__ void lstm_init(const float* __restrict__ h, _Float16* __restrict__ xinit,
                          _Float16* __restrict__ h0b1, _Float16* __restrict__ h1b1,
                          unsigned* __restrict__ slots) {
  int i = blockIdx.x * 256 + threadIdx.x;
  if (i < BD) {
    xinit[i] = (_Float16)h[i];
    h0b1[i] = (_Float16)0.0f;
    h1b1[i] = (_Float16)0.0f;
  }
  if (i < 8192) slots[i] = 0u;   // 4*64 slots, 32-uint (128B) stride
}

__global__ void __launch_bounds__(256, 1) lstm_persist(
    const float* __restrict__ Wih0, const float* __restrict__ Whh0,
    const float* __restrict__ bih0, const float* __restrict__ bhh0,
    const float* __restrict__ Wih1, const float* __restrict__ Whh1,
    const float* __restrict__ bih1, const float* __restrict__ bhh1,
    float* __restrict__ out,
    const _Float16* __restrict__ xinit,
    _Float16* __restrict__ h0b0, _Float16* __restrict__ h0b1,
    _Float16* __restrict__ h1b0, _Float16* __restrict__ h1b1,
    unsigned* __restrict__ slots)
{
  extern __shared__ char smem[];
  float* red = (float*)(smem + SMEM_WBYTES);   // red[4 waves][32 rows][33 pad]
  const int tid = threadIdx.x;
  const int l = tid & 63;
  const int w = tid >> 6;
  const int bid = blockIdx.x;
  // group (b-block) = bits 1..2 so each group sits on an XCD pair if XCD = bid%8
  const int bb = (bid & 7) >> 1;                       // 0..3 batch block
  const int db = ((bid >> 3) << 1) | (bid & 1);        // 0..63 d block
  const int b0 = bb << 6;                              // 64 batch rows
  const int d0 = db << 3;                              // 8 d values

  // ---- stage weights (fp32 -> fp16) into LDS in MFMA B-fragment order ----
  // frag slot (layer, s2=khalf*32+ks, lane): lane&31 = n_local (gate*8+j),
  // lane>>5 = k-group; 8 contiguous k per lane.
#pragma unroll
  for (int L = 0; L < 2; ++L) {
    for (int it = 0; it < 16; ++it) {
      int slot = it * 256 + tid;                 // 0..4095
      int s2 = slot >> 6, lane = slot & 63;
      int khalf = s2 >> 5, ks = s2 & 31;
      int kg = lane >> 5, nl = lane & 31;
      int ng = ((nl >> 3) << 9) + d0 + (nl & 7); // gate*512 + d0 + j
      int col = ks * 16 + kg * 8;
      const float* srcb = khalf ? (L ? Whh1 : Whh0) : (L ? Wih1 : Wih0);
      const float* src = srcb + (size_t)ng * 512 + col;
      half8_t hv;
#pragma unroll
      for (int j = 0; j < 8; ++j) hv[j] = (_Float16)src[j];
      *(half8_t*)(smem + (size_t)L * 65536 + (size_t)slot * 16) = hv;
    }
  }

  // ---- bias (b_ih+b_hh) for this thread's (d0 + tid&7) across 4 gates ----
  float bias0[4], bias1[4];
  {
    int j = tid & 7;
#pragma unroll
    for (int g = 0; g < 4; ++g) {
      int ng = (g << 9) + d0 + j;
      bias0[g] = bih0[ng] + bhh0[ng];
      bias1[g] = bih1[ng] + bhh1[ng];
    }
  }
  float c0s[2] = {0.0f, 0.0f}, c1s[2] = {0.0f, 0.0f};
  unsigned* grpslots = slots + (bb << 6) * 32;
  __syncthreads();

  // ---- 128 sequential stages: s even = layer0, odd = layer1 ----
#pragma unroll 2
  for (int s = 0; s < 128; ++s) {
    const int t = s >> 1;
    const int layer = s & 1;
    const int rb = (t - 1) & 1;   // t=0 -> 1 (zeroed buffers)
    const int wb = t & 1;
    const _Float16* fresh;  // K-half needing barrier(s-1)
    const _Float16* stale;  // K-half from 2 stages back (no wait)
    _Float16* hout;
    if (layer == 0) {
      fresh = (t == 0) ? xinit : (rb ? h1b1 : h1b0);   // x = h1[t-1]
      stale = rb ? h0b1 : h0b0;                        // h0[t-1]
      hout  = wb ? h0b1 : h0b0;
    } else {
      fresh = wb ? h0b1 : h0b0;                        // h0[t]
      stale = rb ? h1b1 : h1b0;                        // h1[t-1]
      hout  = wb ? h1b1 : h1b0;
    }

    // waves 0,1 (fresh half) wait for group barrier s-1; waves 2,3 run ahead
    if (w < 2 && s > 0) {
      unsigned* sl = grpslots + l * 32;
      unsigned v;
      do {
        v = __hip_atomic_load(sl, __ATOMIC_RELAXED, __HIP_MEMORY_SCOPE_AGENT);
      } while (!__all((int)(v >= (unsigned)s)));
      (void)__hip_atomic_load(sl, __ATOMIC_ACQUIRE, __HIP_MEMORY_SCOPE_AGENT);
    }

    // ---- GEMM: wave w: Mtile = w&1 (32 b-rows), khalf = w>>1 ----
    const _Float16* asrc = (w >= 2) ? stale : fresh;
    const _Float16* aptr = asrc + (size_t)(b0 + ((w & 1) << 5) + (l & 31)) * 512
                                + ((l >> 5) << 3);
    int boff = layer * 65536 + ((w >> 1) * 32768) + l * 16;

    f32x16_t acc0, acc1;
#pragma unroll
    for (int r = 0; r < 16; ++r) { acc0[r] = 0.0f; acc1[r] = 0.0f; }

#pragma unroll
    for (int ks = 0; ks < 32; ks += 2) {
      half8_t a0  = *(const half8_t*)(aptr);
      half8_t a1  = *(const half8_t*)(aptr + 16);
      half8_t bv0 = *(const half8_t*)(smem + boff);
      half8_t bv1 = *(const half8_t*)(smem + boff + 1024);
      acc0 = __builtin_amdgcn_mfma_f32_32x32x16_f16(a0, bv0, acc0, 0, 0, 0);
      acc1 = __builtin_amdgcn_mfma_f32_32x32x16_f16(a1, bv1, acc1, 0, 0, 0);
      aptr += 32;
      boff += 2048;
    }

    // ---- C frags -> LDS red[w][row][33] (row = (r&3)+8*(r>>2)+4*(l>>5)) ----
    {
      float* redw = red + w * 1056 + (l & 31);
      const int rbase = (l >> 5) << 2;
#pragma unroll
      for (int r = 0; r < 16; ++r) {
        int row = (r & 3) + ((r >> 2) << 3) + rbase;
        redw[row * 33] = acc0[r] + acc1[r];
      }
    }
    __syncthreads();

    // ---- cell update: thread owns 2 (b,d) pairs; c in registers ----
#pragma unroll
    for (int pp = 0; pp < 2; ++pp) {
      int p = pp * 256 + tid;
      int bl = p >> 3, j = p & 7;
      int base = (bl >> 5) * 1056 + (bl & 31) * 33 + j;
      float vi = red[base]      + red[base + 2112]      + (layer ? bias1[0] : bias0[0]);
      float vf = red[base + 8]  + red[base + 2112 + 8]  + (layer ? bias1[1] : bias0[1]);
      float vg = red[base + 16] + red[base + 2112 + 16] + (layer ? bias1[2] : bias0[2]);
      float vo = red[base + 24] + red[base + 2112 + 24] + (layer ? bias1[3] : bias0[3]);
      float iv = sigmoidf_(vi), fv = sigmoidf_(vf);
      float gv = tanhf_(vg),    ov = sigmoidf_(vo);
      float cold = layer ? c1s[pp] : c0s[pp];
      float c = fv * cold + iv * gv;
      if (layer) c1s[pp] = c; else c0s[pp] = c;
      float hval = ov * tanhf_(c);
      int gidx = (b0 + bl) * 512 + d0 + j;
      hout[gidx] = (_Float16)hval;
      if (layer) out[(size_t)t * BD + gidx] = hval;   // e_seq[t] = h1
    }
    __syncthreads();   // all h stores drained (vmcnt) before arrival
    if (tid == 0)
      __hip_atomic_store(grpslots + db * 32, (unsigned)(s + 1),
                         __ATOMIC_RELEASE, __HIP_MEMORY_SCOPE_AGENT);
  }
}

extern "C" void kernel_launch(void* const* d_in, const int* in_sizes, int n_in,
                              void* d_out, int out_size, void* d_ws, size_t ws_size,
                              hipStream_t stream) {
  const float* h    = (const float*)d_in[0];
  // d_in[1] = T (== 64, compile-time)
  const float* Wih0 = (const float*)d_in[2];
  const float* Whh0 = (const float*)d_in[3];
  const float* bih0 = (const float*)d_in[4];
  const float* bhh0 = (const float*)d_in[5];
  const float* Wih1 = (const float*)d_in[6];
  const float* Whh1 = (const float*)d_in[7];
  const float* bih1 = (const float*)d_in[8];
  const float* bhh1 = (const float*)d_in[9];
  float* out = (float*)d_out;

  char* ws = (char*)d_ws;
  unsigned* slots  = (unsigned*)(ws + WS_SLOTS);
  _Float16* xinit  = (_Float16*)(ws + WS_XINIT);
  _Float16* h0b0   = (_Float16*)(ws + WS_H0B0);
  _Float16* h0b1   = (_Float16*)(ws + WS_H0B1);
  _Float16* h1b0   = (_Float16*)(ws + WS_H1B0);
  _Float16* h1b1   = (_Float16*)(ws + WS_H1B1);

  hipFuncSetAttribute((const void*)lstm_persist,
                      hipFuncAttributeMaxDynamicSharedMemorySize, SMEM_BYTES);

  lstm_init<<<512, 256, 0, stream>>>(h, xinit, h0b1, h1b1, slots);

  void* args[] = { &Wih0, &Whh0, &bih0, &bhh0, &Wih1, &Whh1, &bih1, &bhh1,
                   &out, &xinit, &h0b0, &h0b1, &h1b0, &h1b1, &slots };
  hipLaunchCooperativeKernel((void*)lstm_persist, dim3(256), dim3(256),
                             args, SMEM_BYTES, stream);
}

// Round 2
// 1424.499 us; speedup vs baseline: 1.5152x; 1.5152x over previous
//
#include <hip/hip_runtime.h>

// LSTMDecoder: B=256, D=512, T=64, 2 layers. Persistent cooperative kernel.
// 256 WGs x 256 thr (1/CU). Weights fp16 in LDS (MFMA B-frag order), c-state in
// registers. Cross-WG h exchange via RELAXED agent-scope atomics (sc0 sc1,
// IF$-coherent, NO buffer_wbl2/buffer_inv cache maintenance — that was R0's
// 16 us/stage stall). Flag release = __syncthreads() vmcnt drain + relaxed store.

#define B_DIM 256
#define D_DIM 512
#define T_N   64
#define BD    131072            // B*D
#define SMEM_WBYTES 131072      // 2 layers * 32 gate-rows * 1024 K * 2B (frag order)
#define SMEM_BYTES  (SMEM_WBYTES + 4 * 1056 * 4)   // + red[4][32][33] f32

#define WS_SLOTS  0                       // 4 groups * 64 slots * 128B = 32768
#define WS_XINIT  32768
#define WS_H0B0   (WS_XINIT + BD * 2)
#define WS_H0B1   (WS_H0B0 + BD * 2)
#define WS_H1B0   (WS_H0B1 + BD * 2)
#define WS_H1B1   (WS_H1B0 + BD * 2)     // total ws = 1343488 B

typedef _Float16 half8_t  __attribute__((ext_vector_type(8)));
typedef float    f32x16_t __attribute__((ext_vector_type(16)));
typedef unsigned long long u64;
typedef u64 u64x2_t __attribute__((ext_vector_type(2)));

#define LOADC(p)  __hip_atomic_load((p), __ATOMIC_RELAXED, __HIP_MEMORY_SCOPE_AGENT)
#define STOREC(p, v) __hip_atomic_store((p), (v), __ATOMIC_RELAXED, __HIP_MEMORY_SCOPE_AGENT)

__device__ __forceinline__ float sigmoidf_(float x) {
  float z = __expf(-fabsf(x));
  float s = 1.0f / (1.0f + z);
  return x >= 0.0f ? s : 1.0f - s;
}
__device__ __forceinline__ float tanhf_(float x) {   // overflow-safe tanh
  float z = __expf(-2.0f * fabsf(x));
  float t = (1.0f - z) / (1.0f + z);
  return x >= 0.0f ? t : -t;
}

__device__ __forceinline__ half8_t load_a16(const void* p) {
  u64x2_t w;
  w[0] = LOADC((const u64*)p);
  w[1] = LOADC((const u64*)p + 1);
  return __builtin_bit_cast(half8_t, w);
}

__global__ void lstm_init(const float* __restrict__ h, _Float16* __restrict__ xinit,
                          _Float16* __restrict__ h0b1, _Float16* __restrict__ h1b1,
                          unsigned* __restrict__ slots) {
  int i = blockIdx.x * 256 + threadIdx.x;
  if (i < BD) {
    xinit[i] = (_Float16)h[i];
    h0b1[i] = (_Float16)0.0f;
    h1b1[i] = (_Float16)0.0f;
  }
  if (i < 8192) slots[i] = 0u;   // 4*64 slots, 32-uint (128B) stride
}

__global__ void __launch_bounds__(256, 1) lstm_persist(
    const float* __restrict__ Wih0, const float* __restrict__ Whh0,
    const float* __restrict__ bih0, const float* __restrict__ bhh0,
    const float* __restrict__ Wih1, const float* __restrict__ Whh1,
    const float* __restrict__ bih1, const float* __restrict__ bhh1,
    float* __restrict__ out,
    const _Float16* __restrict__ xinit,
    _Float16* __restrict__ h0b0, _Float16* __restrict__ h0b1,
    _Float16* __restrict__ h1b0, _Float16* __restrict__ h1b1,
    unsigned* __restrict__ slots)
{
  extern __shared__ char smem[];
  float* red = (float*)(smem + SMEM_WBYTES);   // red[4 waves][32 rows][33 pad]
  const int tid = threadIdx.x;
  const int l = tid & 63;
  const int w = tid >> 6;
  const int bid = blockIdx.x;
  // group (b-block) = bits 1..2 so each group spans an XCD pair if XCD = bid%8
  const int bb = (bid & 7) >> 1;                       // 0..3 batch block
  const int db = ((bid >> 3) << 1) | (bid & 1);        // 0..63 d block
  const int b0 = bb << 6;                              // 64 batch rows
  const int d0 = db << 3;                              // 8 d values

  // ---- stage weights (fp32 -> fp16) into LDS in MFMA B-fragment order ----
#pragma unroll
  for (int L = 0; L < 2; ++L) {
    for (int it = 0; it < 16; ++it) {
      int slot = it * 256 + tid;                 // 0..4095
      int s2 = slot >> 6, lane = slot & 63;
      int khalf = s2 >> 5, ks = s2 & 31;
      int kg = lane >> 5, nl = lane & 31;
      int ng = ((nl >> 3) << 9) + d0 + (nl & 7); // gate*512 + d0 + j
      int col = ks * 16 + kg * 8;
      const float* srcb = khalf ? (L ? Whh1 : Whh0) : (L ? Wih1 : Wih0);
      const float* src = srcb + (size_t)ng * 512 + col;
      half8_t hv;
#pragma unroll
      for (int j = 0; j < 8; ++j) hv[j] = (_Float16)src[j];
      *(half8_t*)(smem + (size_t)L * 65536 + (size_t)slot * 16) = hv;
    }
  }

  // ---- bias (b_ih+b_hh) for this thread's two d values (j0, j0+1) ----
  const int cbl = tid >> 2;            // batch row within group owned in cell phase
  const int j0 = (tid & 3) << 1;       // even d offset
  float bias0[4][2], bias1[4][2];
#pragma unroll
  for (int g = 0; g < 4; ++g) {
#pragma unroll
    for (int p = 0; p < 2; ++p) {
      int ng = (g << 9) + d0 + j0 + p;
      bias0[g][p] = bih0[ng] + bhh0[ng];
      bias1[g][p] = bih1[ng] + bhh1[ng];
    }
  }
  float c0s[2] = {0.0f, 0.0f}, c1s[2] = {0.0f, 0.0f};
  unsigned* grpslots = slots + (bb << 6) * 32;
  __syncthreads();

  // ---- 128 sequential stages: s even = layer0, odd = layer1 ----
#pragma unroll 2
  for (int s = 0; s < 128; ++s) {
    const int t = s >> 1;
    const int layer = s & 1;
    const int rb = (t - 1) & 1;   // t=0 -> 1 (zeroed buffers)
    const int wb = t & 1;
    const _Float16* fresh;  // K-half needing barrier(s-1)
    const _Float16* stale;  // K-half from 2 stages back (no wait)
    _Float16* hout;
    if (layer == 0) {
      fresh = (t == 0) ? xinit : (rb ? h1b1 : h1b0);   // x = h1[t-1]
      stale = rb ? h0b1 : h0b0;                        // h0[t-1]
      hout  = wb ? h0b1 : h0b0;
    } else {
      fresh = wb ? h0b1 : h0b0;                        // h0[t]
      stale = rb ? h1b1 : h1b0;                        // h1[t-1]
      hout  = wb ? h1b1 : h1b0;
    }

    // waves 0,1 (fresh half) wait for group barrier s-1; waves 2,3 run ahead
    if (w < 2 && s > 0) {
      unsigned* sl = grpslots + l * 32;
      unsigned v;
      do {
        v = LOADC(sl);
      } while (!__all((int)(v >= (unsigned)s)));
      // no acquire: A-loads below are agent-scope (sc1) themselves
    }

    // ---- GEMM: wave w: Mtile = w&1 (32 b-rows), khalf = w>>1 ----
    const _Float16* asrc = (w >= 2) ? stale : fresh;
    const char* ap = (const char*)(asrc + (size_t)(b0 + ((w & 1) << 5) + (l & 31)) * 512
                                        + ((l >> 5) << 3));
    int boff = layer * 65536 + ((w >> 1) * 32768) + l * 16;

    f32x16_t acc0, acc1;
#pragma unroll
    for (int r = 0; r < 16; ++r) { acc0[r] = 0.0f; acc1[r] = 0.0f; }

#pragma unroll
    for (int ks = 0; ks < 16; ++ks) {
      half8_t a0  = load_a16(ap);
      half8_t a1  = load_a16(ap + 32);
      half8_t bv0 = *(const half8_t*)(smem + boff);
      half8_t bv1 = *(const half8_t*)(smem + boff + 1024);
      acc0 = __builtin_amdgcn_mfma_f32_32x32x16_f16(a0, bv0, acc0, 0, 0, 0);
      acc1 = __builtin_amdgcn_mfma_f32_32x32x16_f16(a1, bv1, acc1, 0, 0, 0);
      ap += 64;
      boff += 2048;
    }

    // ---- C frags -> LDS red[w][row][33] (row = (r&3)+8*(r>>2)+4*(l>>5)) ----
    {
      float* redw = red + w * 1056 + (l & 31);
      const int rbase = (l >> 5) << 2;
#pragma unroll
      for (int r = 0; r < 16; ++r) {
        int row = (r & 3) + ((r >> 2) << 3) + rbase;
        redw[row * 33] = acc0[r] + acc1[r];
      }
    }
    __syncthreads();

    // ---- cell update: thread owns (cbl, j0) and (cbl, j0+1); c in regs ----
    {
      const int base = (cbl >> 5) * 1056 + (cbl & 31) * 33 + j0;
      float hv[2];
#pragma unroll
      for (int p = 0; p < 2; ++p) {
        float vi = red[base + p]      + red[base + 2112 + p]      + (layer ? bias1[0][p] : bias0[0][p]);
        float vf = red[base + 8 + p]  + red[base + 2112 + 8 + p]  + (layer ? bias1[1][p] : bias0[1][p]);
        float vg = red[base + 16 + p] + red[base + 2112 + 16 + p] + (layer ? bias1[2][p] : bias0[2][p]);
        float vo = red[base + 24 + p] + red[base + 2112 + 24 + p] + (layer ? bias1[3][p] : bias0[3][p]);
        float iv = sigmoidf_(vi), fv = sigmoidf_(vf);
        float gv = tanhf_(vg),    ov = sigmoidf_(vo);
        float cold = layer ? c1s[p] : c0s[p];
        float c = fv * cold + iv * gv;
        if (layer) c1s[p] = c; else c0s[p] = c;
        hv[p] = ov * tanhf_(c);
      }
      const int gidx = (b0 + cbl) * 512 + d0 + j0;
      unsigned hu = ((unsigned)__builtin_bit_cast(unsigned short, (_Float16)hv[0])) |
                    ((unsigned)__builtin_bit_cast(unsigned short, (_Float16)hv[1]) << 16);
      STOREC((unsigned*)&hout[gidx], hu);            // coherent, no fence
      if (layer) {
        float* op = out + (size_t)t * BD + gidx;
        op[0] = hv[0]; op[1] = hv[1];                // plain store; kernel-end flush
      }
    }
    asm volatile("s_waitcnt vmcnt(0)" ::: "memory"); // stores acked at IF$
    __syncthreads();                                  // all threads' stores drained
    if (tid == 0)
      STOREC(grpslots + db * 32, (unsigned)(s + 1)); // relaxed: barrier did the release
  }
}

extern "C" void kernel_launch(void* const* d_in, const int* in_sizes, int n_in,
                              void* d_out, int out_size, void* d_ws, size_t ws_size,
                              hipStream_t stream) {
  const float* h    = (const float*)d_in[0];
  // d_in[1] = T (== 64, compile-time)
  const float* Wih0 = (const float*)d_in[2];
  const float* Whh0 = (const float*)d_in[3];
  const float* bih0 = (const float*)d_in[4];
  const float* bhh0 = (const float*)d_in[5];
  const float* Wih1 = (const float*)d_in[6];
  const float* Whh1 = (const float*)d_in[7];
  const float* bih1 = (const float*)d_in[8];
  const float* bhh1 = (const float*)d_in[9];
  float* out = (float*)d_out;

  char* ws = (char*)d_ws;
  unsigned* slots  = (unsigned*)(ws + WS_SLOTS);
  _Float16* xinit  = (_Float16*)(ws + WS_XINIT);
  _Float16* h0b0   = (_Float16*)(ws + WS_H0B0);
  _Float16* h0b1   = (_Float16*)(ws + WS_H0B1);
  _Float16* h1b0   = (_Float16*)(ws + WS_H1B0);
  _Float16* h1b1   = (_Float16*)(ws + WS_H1B1);

  hipFuncSetAttribute((const void*)lstm_persist,
                      hipFuncAttributeMaxDynamicSharedMemorySize, SMEM_BYTES);

  lstm_init<<<512, 256, 0, stream>>>(h, xinit, h0b1, h1b1, slots);

  void* args[] = { &Wih0, &Whh0, &bih0, &bhh0, &Wih1, &Whh1, &bih1, &bhh1,
                   &out, &xinit, &h0b0, &h0b1, &h1b0, &h1b1, &slots };
  hipLaunchCooperativeKernel((void*)lstm_persist, dim3(256), dim3(256),
                             args, SMEM_BYTES, stream);
}

// Round 4
// 1012.782 us; speedup vs baseline: 2.1311x; 1.4065x over previous
//
#include <hip/hip_runtime.h>

// LSTMDecoder: B=256, D=512, T=64, 2 layers. Persistent cooperative kernel.
// 256 WGs x 256 thr (1/CU, 1 wave/SIMD). Weights fp16 in LDS (MFMA B-frag
// order), c-state in registers. Cross-WG h exchange: coherent (sc0 sc1,
// IF$-level) 16B asm loads, burst-issued 32-deep so each stage pays ONE IF$
// latency. R3 bug: inline-asm loads need an EXPLICIT s_waitcnt vmcnt(0)
// before use — the compiler only auto-inserts waits for loads it emits itself.

#define B_DIM 256
#define D_DIM 512
#define T_N   64
#define BD    131072            // B*D
#define SMEM_WBYTES 131072      // 2 layers * 32 gate-rows * 1024 K * 2B (frag order)
#define SMEM_BYTES  (SMEM_WBYTES + 4 * 1056 * 4)   // + red[4][32][33] f32

#define WS_SLOTS  0                       // 4 groups * 64 slots * 128B = 32768
#define WS_XINIT  32768
#define WS_H0B0   (WS_XINIT + BD * 2)
#define WS_H0B1   (WS_H0B0 + BD * 2)
#define WS_H1B0   (WS_H0B1 + BD * 2)
#define WS_H1B1   (WS_H1B0 + BD * 2)     // total ws = 1343488 B

typedef _Float16 half8_t  __attribute__((ext_vector_type(8)));
typedef float    f32x16_t __attribute__((ext_vector_type(16)));
typedef float    f32x4_t  __attribute__((ext_vector_type(4)));

#define LOADC(p)  __hip_atomic_load((p), __ATOMIC_RELAXED, __HIP_MEMORY_SCOPE_AGENT)
#define STOREC(p, v) __hip_atomic_store((p), (v), __ATOMIC_RELAXED, __HIP_MEMORY_SCOPE_AGENT)

__device__ __forceinline__ float sigmoidf_(float x) {
  float z = __expf(-fabsf(x));
  float s = 1.0f / (1.0f + z);
  return x >= 0.0f ? s : 1.0f - s;
}
__device__ __forceinline__ float tanhf_(float x) {   // overflow-safe tanh
  float z = __expf(-2.0f * fabsf(x));
  float t = (1.0f - z) / (1.0f + z);
  return x >= 0.0f ? t : -t;
}

// 16B coherent load: bypass L1/L2 (sc0 sc1), served by IF$. No atomicity
// needed — happens-before comes from the slot flags; tearing is of settled data.
// CALLER must s_waitcnt vmcnt(0) before consuming the result!
__device__ __forceinline__ f32x4_t load_cv16(const void* p) {
  f32x4_t r;
  asm volatile("global_load_dwordx4 %0, %1, off sc0 sc1"
               : "=v"(r) : "v"(p) : "memory");
  return r;
}

__global__ void lstm_init(const float* __restrict__ h, _Float16* __restrict__ xinit,
                          _Float16* __restrict__ h0b1, _Float16* __restrict__ h1b1,
                          unsigned* __restrict__ slots) {
  int i = blockIdx.x * 256 + threadIdx.x;
  if (i < BD) {
    xinit[i] = (_Float16)h[i];
    h0b1[i] = (_Float16)0.0f;
    h1b1[i] = (_Float16)0.0f;
  }
  if (i < 8192) slots[i] = 0u;   // 4*64 slots, 32-uint (128B) stride
}

__global__ void __launch_bounds__(256, 1) lstm_persist(
    const float* __restrict__ Wih0, const float* __restrict__ Whh0,
    const float* __restrict__ bih0, const float* __restrict__ bhh0,
    const float* __restrict__ Wih1, const float* __restrict__ Whh1,
    const float* __restrict__ bih1, const float* __restrict__ bhh1,
    float* __restrict__ out,
    const _Float16* __restrict__ xinit,
    _Float16* __restrict__ h0b0, _Float16* __restrict__ h0b1,
    _Float16* __restrict__ h1b0, _Float16* __restrict__ h1b1,
    unsigned* __restrict__ slots)
{
  extern __shared__ char smem[];
  float* red = (float*)(smem + SMEM_WBYTES);   // red[4 waves][32 rows][33 pad]
  const int tid = threadIdx.x;
  const int l = tid & 63;
  const int w = tid >> 6;
  const int bid = blockIdx.x;
  const int bb = (bid & 7) >> 1;                       // 0..3 batch block
  const int db = ((bid >> 3) << 1) | (bid & 1);        // 0..63 d block
  const int b0 = bb << 6;                              // 64 batch rows
  const int d0 = db << 3;                              // 8 d values

  // ---- stage weights (fp32 -> fp16) into LDS in MFMA B-fragment order ----
#pragma unroll
  for (int L = 0; L < 2; ++L) {
    for (int it = 0; it < 16; ++it) {
      int slot = it * 256 + tid;                 // 0..4095
      int s2 = slot >> 6, lane = slot & 63;
      int khalf = s2 >> 5, ks = s2 & 31;
      int kg = lane >> 5, nl = lane & 31;
      int ng = ((nl >> 3) << 9) + d0 + (nl & 7); // gate*512 + d0 + j
      int col = ks * 16 + kg * 8;
      const float* srcb = khalf ? (L ? Whh1 : Whh0) : (L ? Wih1 : Wih0);
      const float* src = srcb + (size_t)ng * 512 + col;
      half8_t hv;
#pragma unroll
      for (int j = 0; j < 8; ++j) hv[j] = (_Float16)src[j];
      *(half8_t*)(smem + (size_t)L * 65536 + (size_t)slot * 16) = hv;
    }
  }

  // ---- bias (b_ih+b_hh) for this thread's two d values (j0, j0+1) ----
  const int cbl = tid >> 2;            // batch row (within group) owned in cell phase
  const int j0 = (tid & 3) << 1;       // even d offset
  float bias0[4][2], bias1[4][2];
#pragma unroll
  for (int g = 0; g < 4; ++g) {
#pragma unroll
    for (int p = 0; p < 2; ++p) {
      int ng = (g << 9) + d0 + j0 + p;
      bias0[g][p] = bih0[ng] + bhh0[ng];
      bias1[g][p] = bih1[ng] + bhh1[ng];
    }
  }
  float c0s[2] = {0.0f, 0.0f}, c1s[2] = {0.0f, 0.0f};
  unsigned* grpslots = slots + (bb << 6) * 32;
  __syncthreads();

  // ---- 128 sequential stages: s even = layer0, odd = layer1 ----
  for (int s = 0; s < 128; ++s) {
    const int t = s >> 1;
    const int layer = s & 1;
    const int rb = (t - 1) & 1;   // t=0 -> 1 (zeroed buffers)
    const int wb = t & 1;
    const _Float16* fresh;  // K-half needing barrier(s-1)
    const _Float16* stale;  // K-half from 2 stages back (no wait)
    _Float16* hout;
    if (layer == 0) {
      fresh = (t == 0) ? xinit : (rb ? h1b1 : h1b0);   // x = h1[t-1]
      stale = rb ? h0b1 : h0b0;                        // h0[t-1]
      hout  = wb ? h0b1 : h0b0;
    } else {
      fresh = wb ? h0b1 : h0b0;                        // h0[t]
      stale = rb ? h1b1 : h1b0;                        // h1[t-1]
      hout  = wb ? h1b1 : h1b0;
    }

    // waves 0,1 (fresh half) wait for group barrier s-1; waves 2,3 run ahead
    if (w < 2 && s > 0) {
      unsigned* sl = grpslots + l * 32;
      unsigned v;
      do {
        v = LOADC(sl);
      } while (!__all((int)(v >= (unsigned)s)));
      asm volatile("" ::: "memory");   // pin A-loads below the poll
    }

    // ---- GEMM: wave w: M-tile = w&1 (32 b-rows), K-half = w>>1 ----
    const _Float16* asrc = (w >= 2) ? stale : fresh;
    const char* ap = (const char*)(asrc + (size_t)(b0 + ((w & 1) << 5) + (l & 31)) * 512
                                        + ((l >> 5) << 3));
    int boff = layer * 65536 + ((w >> 1) * 32768) + l * 16;

    // burst-issue the whole A panel: 32 x 16B coherent loads, one IF$ latency
    f32x4_t va[32];
#pragma unroll
    for (int j = 0; j < 32; ++j) va[j] = load_cv16(ap + 32 * j);
    // drain OUR loads (prev-stage stores were drained before the flag release,
    // so vmcnt pending == these 32 loads). Without this: undefined VGPRs (R3 NaN).
    asm volatile("s_waitcnt vmcnt(0)" ::: "memory");

    f32x16_t acc0, acc1;
#pragma unroll
    for (int r = 0; r < 16; ++r) { acc0[r] = 0.0f; acc1[r] = 0.0f; }

#pragma unroll
    for (int ks = 0; ks < 16; ++ks) {
      half8_t a0  = __builtin_bit_cast(half8_t, va[2 * ks]);
      half8_t a1  = __builtin_bit_cast(half8_t, va[2 * ks + 1]);
      half8_t bv0 = *(const half8_t*)(smem + boff);
      half8_t bv1 = *(const half8_t*)(smem + boff + 1024);
      acc0 = __builtin_amdgcn_mfma_f32_32x32x16_f16(a0, bv0, acc0, 0, 0, 0);
      acc1 = __builtin_amdgcn_mfma_f32_32x32x16_f16(a1, bv1, acc1, 0, 0, 0);
      boff += 2048;
    }

    // ---- C frags -> LDS red[w][row][33] (row = (r&3)+8*(r>>2)+4*(l>>5)) ----
    {
      float* redw = red + w * 1056 + (l & 31);
      const int rbase = (l >> 5) << 2;
#pragma unroll
      for (int r = 0; r < 16; ++r) {
        int row = (r & 3) + ((r >> 2) << 3) + rbase;
        redw[row * 33] = acc0[r] + acc1[r];
      }
    }
    __syncthreads();

    // ---- cell update: thread owns (cbl, j0) and (cbl, j0+1); c in regs ----
    {
      const int base = (cbl >> 5) * 1056 + (cbl & 31) * 33 + j0;
      float hv[2];
#pragma unroll
      for (int p = 0; p < 2; ++p) {
        float vi = red[base + p]      + red[base + 2112 + p]      + (layer ? bias1[0][p] : bias0[0][p]);
        float vf = red[base + 8 + p]  + red[base + 2112 + 8 + p]  + (layer ? bias1[1][p] : bias0[1][p]);
        float vg = red[base + 16 + p] + red[base + 2112 + 16 + p] + (layer ? bias1[2][p] : bias0[2][p]);
        float vo = red[base + 24 + p] + red[base + 2112 + 24 + p] + (layer ? bias1[3][p] : bias0[3][p]);
        float iv = sigmoidf_(vi), fv = sigmoidf_(vf);
        float gv = tanhf_(vg),    ov = sigmoidf_(vo);
        float cold = layer ? c1s[p] : c0s[p];
        float c = fv * cold + iv * gv;
        if (layer) c1s[p] = c; else c0s[p] = c;
        hv[p] = ov * tanhf_(c);
      }
      const int gidx = (b0 + cbl) * 512 + d0 + j0;
      unsigned hu = ((unsigned)__builtin_bit_cast(unsigned short, (_Float16)hv[0])) |
                    ((unsigned)__builtin_bit_cast(unsigned short, (_Float16)hv[1]) << 16);
      STOREC((unsigned*)&hout[gidx], hu);            // coherent, no fence
      if (layer) {
        float* op = out + (size_t)t * BD + gidx;
        op[0] = hv[0]; op[1] = hv[1];                // plain store; kernel-end flush
      }
    }
    asm volatile("s_waitcnt vmcnt(0)" ::: "memory"); // stores acked at IF$
    __syncthreads();                                  // all threads' stores drained
    if (tid == 0)
      STOREC(grpslots + db * 32, (unsigned)(s + 1)); // relaxed: barrier did the release
  }
}

extern "C" void kernel_launch(void* const* d_in, const int* in_sizes, int n_in,
                              void* d_out, int out_size, void* d_ws, size_t ws_size,
                              hipStream_t stream) {
  const float* h    = (const float*)d_in[0];
  // d_in[1] = T (== 64, compile-time)
  const float* Wih0 = (const float*)d_in[2];
  const float* Whh0 = (const float*)d_in[3];
  const float* bih0 = (const float*)d_in[4];
  const float* bhh0 = (const float*)d_in[5];
  const float* Wih1 = (const float*)d_in[6];
  const float* Whh1 = (const float*)d_in[7];
  const float* bih1 = (const float*)d_in[8];
  const float* bhh1 = (const float*)d_in[9];
  float* out = (float*)d_out;

  char* ws = (char*)d_ws;
  unsigned* slots  = (unsigned*)(ws + WS_SLOTS);
  _Float16* xinit  = (_Float16*)(ws + WS_XINIT);
  _Float16* h0b0   = (_Float16*)(ws + WS_H0B0);
  _Float16* h0b1   = (_Float16*)(ws + WS_H0B1);
  _Float16* h1b0   = (_Float16*)(ws + WS_H1B0);
  _Float16* h1b1   = (_Float16*)(ws + WS_H1B1);

  hipFuncSetAttribute((const void*)lstm_persist,
                      hipFuncAttributeMaxDynamicSharedMemorySize, SMEM_BYTES);

  lstm_init<<<512, 256, 0, stream>>>(h, xinit, h0b1, h1b1, slots);

  void* args[] = { &Wih0, &Whh0, &bih0, &bhh0, &Wih1, &Whh1, &bih1, &bhh1,
                   &out, &xinit, &h0b0, &h0b1, &h1b0, &h1b1, &slots };
  hipLaunchCooperativeKernel((void*)lstm_persist, dim3(256), dim3(256),
                             args, SMEM_BYTES, stream);
}

// Round 5
// 958.875 us; speedup vs baseline: 2.2510x; 1.0562x over previous
//
#include <hip/hip_runtime.h>

// LSTMDecoder: B=256, D=512, T=64, 2 layers. Persistent cooperative kernel.
// 256 WGs x 256 thr (1/CU, 1 wave/SIMD). Weights fp16 in LDS (MFMA B-frag
// order), c-state in registers. Cross-WG h exchange: coherent (sc0 sc1)
// 16B asm loads. R4 lesson: a 32-deep burst (128 VGPRs live) got spilled to
// scratch (VGPR=104, SGPR=112) re-serializing the loads — so R5 uses TWO
// 16-load bursts (64 VGPRs live) with vmcnt(0) each: 2 IF$ latencies/stage,
// no spill. out stores moved after the flag release (off the critical path).

#define B_DIM 256
#define D_DIM 512
#define T_N   64
#define BD    131072            // B*D
#define SMEM_WBYTES 131072      // 2 layers * 32 gate-rows * 1024 K * 2B (frag order)
#define SMEM_BYTES  (SMEM_WBYTES + 4 * 1056 * 4)   // + red[4][32][33] f32

#define WS_SLOTS  0                       // 4 groups * 64 slots * 128B = 32768
#define WS_XINIT  32768
#define WS_H0B0   (WS_XINIT + BD * 2)
#define WS_H0B1   (WS_H0B0 + BD * 2)
#define WS_H1B0   (WS_H0B1 + BD * 2)
#define WS_H1B1   (WS_H1B0 + BD * 2)     // total ws = 1343488 B

typedef _Float16 half8_t  __attribute__((ext_vector_type(8)));
typedef float    f32x16_t __attribute__((ext_vector_type(16)));
typedef float    f32x4_t  __attribute__((ext_vector_type(4)));

#define LOADC(p)  __hip_atomic_load((p), __ATOMIC_RELAXED, __HIP_MEMORY_SCOPE_AGENT)
#define STOREC(p, v) __hip_atomic_store((p), (v), __ATOMIC_RELAXED, __HIP_MEMORY_SCOPE_AGENT)

__device__ __forceinline__ float sigmoidf_(float x) {
  float z = __expf(-fabsf(x));
  float s = 1.0f / (1.0f + z);
  return x >= 0.0f ? s : 1.0f - s;
}
__device__ __forceinline__ float tanhf_(float x) {   // overflow-safe tanh
  float z = __expf(-2.0f * fabsf(x));
  float t = (1.0f - z) / (1.0f + z);
  return x >= 0.0f ? t : -t;
}

// 16B coherent load: bypass L1/L2 (sc0 sc1), served by IF$. No atomicity
// needed — happens-before comes from the slot flags; tearing is of settled data.
// CALLER must s_waitcnt vmcnt(0) before consuming the result!
__device__ __forceinline__ f32x4_t load_cv16(const void* p) {
  f32x4_t r;
  asm volatile("global_load_dwordx4 %0, %1, off sc0 sc1"
               : "=v"(r) : "v"(p) : "memory");
  return r;
}

__global__ void lstm_init(const float* __restrict__ h, _Float16* __restrict__ xinit,
                          _Float16* __restrict__ h0b1, _Float16* __restrict__ h1b1,
                          unsigned* __restrict__ slots) {
  int i = blockIdx.x * 256 + threadIdx.x;
  if (i < BD) {
    xinit[i] = (_Float16)h[i];
    h0b1[i] = (_Float16)0.0f;
    h1b1[i] = (_Float16)0.0f;
  }
  if (i < 8192) slots[i] = 0u;   // 4*64 slots, 32-uint (128B) stride
}

__global__ void __launch_bounds__(256, 1) lstm_persist(
    const float* __restrict__ Wih0, const float* __restrict__ Whh0,
    const float* __restrict__ bih0, const float* __restrict__ bhh0,
    const float* __restrict__ Wih1, const float* __restrict__ Whh1,
    const float* __restrict__ bih1, const float* __restrict__ bhh1,
    float* __restrict__ out,
    const _Float16* __restrict__ xinit,
    _Float16* __restrict__ h0b0, _Float16* __restrict__ h0b1,
    _Float16* __restrict__ h1b0, _Float16* __restrict__ h1b1,
    unsigned* __restrict__ slots)
{
  extern __shared__ char smem[];
  float* red = (float*)(smem + SMEM_WBYTES);   // red[4 waves][32 rows][33 pad]
  const int tid = threadIdx.x;
  const int l = tid & 63;
  const int w = tid >> 6;
  const int bid = blockIdx.x;
  const int bb = (bid & 7) >> 1;                       // 0..3 batch block
  const int db = ((bid >> 3) << 1) | (bid & 1);        // 0..63 d block
  const int b0 = bb << 6;                              // 64 batch rows
  const int d0 = db << 3;                              // 8 d values

  // ---- stage weights (fp32 -> fp16) into LDS in MFMA B-fragment order ----
#pragma unroll
  for (int L = 0; L < 2; ++L) {
    for (int it = 0; it < 16; ++it) {
      int slot = it * 256 + tid;                 // 0..4095
      int s2 = slot >> 6, lane = slot & 63;
      int khalf = s2 >> 5, ks = s2 & 31;
      int kg = lane >> 5, nl = lane & 31;
      int ng = ((nl >> 3) << 9) + d0 + (nl & 7); // gate*512 + d0 + j
      int col = ks * 16 + kg * 8;
      const float* srcb = khalf ? (L ? Whh1 : Whh0) : (L ? Wih1 : Wih0);
      const float* src = srcb + (size_t)ng * 512 + col;
      half8_t hv;
#pragma unroll
      for (int j = 0; j < 8; ++j) hv[j] = (_Float16)src[j];
      *(half8_t*)(smem + (size_t)L * 65536 + (size_t)slot * 16) = hv;
    }
  }

  // ---- bias (b_ih+b_hh) for this thread's two d values (j0, j0+1) ----
  const int cbl = tid >> 2;            // batch row (within group) owned in cell phase
  const int j0 = (tid & 3) << 1;       // even d offset
  float bias0[4][2], bias1[4][2];
#pragma unroll
  for (int g = 0; g < 4; ++g) {
#pragma unroll
    for (int p = 0; p < 2; ++p) {
      int ng = (g << 9) + d0 + j0 + p;
      bias0[g][p] = bih0[ng] + bhh0[ng];
      bias1[g][p] = bih1[ng] + bhh1[ng];
    }
  }
  float c0s[2] = {0.0f, 0.0f}, c1s[2] = {0.0f, 0.0f};
  unsigned* grpslots = slots + (bb << 6) * 32;
  __syncthreads();

  // ---- 128 sequential stages: s even = layer0, odd = layer1 ----
  for (int s = 0; s < 128; ++s) {
    const int t = s >> 1;
    const int layer = s & 1;
    const int rb = (t - 1) & 1;   // t=0 -> 1 (zeroed buffers)
    const int wb = t & 1;
    const _Float16* fresh;  // K-half needing barrier(s-1)
    const _Float16* stale;  // K-half from 2 stages back (no wait)
    _Float16* hout;
    if (layer == 0) {
      fresh = (t == 0) ? xinit : (rb ? h1b1 : h1b0);   // x = h1[t-1]
      stale = rb ? h0b1 : h0b0;                        // h0[t-1]
      hout  = wb ? h0b1 : h0b0;
    } else {
      fresh = wb ? h0b1 : h0b0;                        // h0[t]
      stale = rb ? h1b1 : h1b0;                        // h1[t-1]
      hout  = wb ? h1b1 : h1b0;
    }

    // waves 0,1 (fresh half) wait for group barrier s-1; waves 2,3 run ahead
    if (w < 2 && s > 0) {
      unsigned* sl = grpslots + l * 32;
      unsigned v;
      do {
        v = LOADC(sl);
      } while (!__all((int)(v >= (unsigned)s)));
      asm volatile("" ::: "memory");   // pin A-loads below the poll
    }

    // ---- GEMM: wave w: M-tile = w&1 (32 b-rows), K-half = w>>1 ----
    const _Float16* asrc = (w >= 2) ? stale : fresh;
    const char* ap = (const char*)(asrc + (size_t)(b0 + ((w & 1) << 5) + (l & 31)) * 512
                                        + ((l >> 5) << 3));
    int boff = layer * 65536 + ((w >> 1) * 32768) + l * 16;

    f32x16_t acc0, acc1;
#pragma unroll
    for (int r = 0; r < 16; ++r) { acc0[r] = 0.0f; acc1[r] = 0.0f; }

    // A panel in 2 bursts of 16x16B coherent loads (64 VGPR live -> no spill)
    f32x4_t va[16];
#pragma unroll
    for (int half = 0; half < 2; ++half) {
#pragma unroll
      for (int j = 0; j < 16; ++j) va[j] = load_cv16(ap + half * 512 + 32 * j);
      asm volatile("s_waitcnt vmcnt(0)" ::: "memory");  // drain OUR 16 loads
#pragma unroll
      for (int ks = 0; ks < 8; ++ks) {
        half8_t a0  = __builtin_bit_cast(half8_t, va[2 * ks]);
        half8_t a1  = __builtin_bit_cast(half8_t, va[2 * ks + 1]);
        half8_t bv0 = *(const half8_t*)(smem + boff);
        half8_t bv1 = *(const half8_t*)(smem + boff + 1024);
        acc0 = __builtin_amdgcn_mfma_f32_32x32x16_f16(a0, bv0, acc0, 0, 0, 0);
        acc1 = __builtin_amdgcn_mfma_f32_32x32x16_f16(a1, bv1, acc1, 0, 0, 0);
        boff += 2048;
      }
    }

    // ---- C frags -> LDS red[w][row][33] (row = (r&3)+8*(r>>2)+4*(l>>5)) ----
    {
      float* redw = red + w * 1056 + (l & 31);
      const int rbase = (l >> 5) << 2;
#pragma unroll
      for (int r = 0; r < 16; ++r) {
        int row = (r & 3) + ((r >> 2) << 3) + rbase;
        redw[row * 33] = acc0[r] + acc1[r];
      }
    }
    __syncthreads();

    // ---- cell update: thread owns (cbl, j0) and (cbl, j0+1); c in regs ----
    float hv[2];
    int gidx;
    {
      const int base = (cbl >> 5) * 1056 + (cbl & 31) * 33 + j0;
#pragma unroll
      for (int p = 0; p < 2; ++p) {
        float vi = red[base + p]      + red[base + 2112 + p]      + (layer ? bias1[0][p] : bias0[0][p]);
        float vf = red[base + 8 + p]  + red[base + 2112 + 8 + p]  + (layer ? bias1[1][p] : bias0[1][p]);
        float vg = red[base + 16 + p] + red[base + 2112 + 16 + p] + (layer ? bias1[2][p] : bias0[2][p]);
        float vo = red[base + 24 + p] + red[base + 2112 + 24 + p] + (layer ? bias1[3][p] : bias0[3][p]);
        float iv = sigmoidf_(vi), fv = sigmoidf_(vf);
        float gv = tanhf_(vg),    ov = sigmoidf_(vo);
        float cold = layer ? c1s[p] : c0s[p];
        float c = fv * cold + iv * gv;
        if (layer) c1s[p] = c; else c0s[p] = c;
        hv[p] = ov * tanhf_(c);
      }
      gidx = (b0 + cbl) * 512 + d0 + j0;
      unsigned hu = ((unsigned)__builtin_bit_cast(unsigned short, (_Float16)hv[0])) |
                    ((unsigned)__builtin_bit_cast(unsigned short, (_Float16)hv[1]) << 16);
      STOREC((unsigned*)&hout[gidx], hu);            // coherent, no fence
    }
    asm volatile("s_waitcnt vmcnt(0)" ::: "memory"); // h stores acked at IF$
    __syncthreads();                                  // all threads' stores drained
    if (tid == 0)
      STOREC(grpslots + db * 32, (unsigned)(s + 1)); // relaxed: barrier did the release
    if (layer) {                                      // off the critical path
      float* op = out + (size_t)t * BD + gidx;
      op[0] = hv[0]; op[1] = hv[1];
    }
  }
}

extern "C" void kernel_launch(void* const* d_in, const int* in_sizes, int n_in,
                              void* d_out, int out_size, void* d_ws, size_t ws_size,
                              hipStream_t stream) {
  const float* h    = (const float*)d_in[0];
  // d_in[1] = T (== 64, compile-time)
  const float* Wih0 = (const float*)d_in[2];
  const float* Whh0 = (const float*)d_in[3];
  const float* bih0 = (const float*)d_in[4];
  const float* bhh0 = (const float*)d_in[5];
  const float* Wih1 = (const float*)d_in[6];
  const float* Whh1 = (const float*)d_in[7];
  const float* bih1 = (const float*)d_in[8];
  const float* bhh1 = (const float*)d_in[9];
  float* out = (float*)d_out;

  char* ws = (char*)d_ws;
  unsigned* slots  = (unsigned*)(ws + WS_SLOTS);
  _Float16* xinit  = (_Float16*)(ws + WS_XINIT);
  _Float16* h0b0   = (_Float16*)(ws + WS_H0B0);
  _Float16* h0b1   = (_Float16*)(ws + WS_H0B1);
  _Float16* h1b0   = (_Float16*)(ws + WS_H1B0);
  _Float16* h1b1   = (_Float16*)(ws + WS_H1B1);

  hipFuncSetAttribute((const void*)lstm_persist,
                      hipFuncAttributeMaxDynamicSharedMemorySize, SMEM_BYTES);

  lstm_init<<<512, 256, 0, stream>>>(h, xinit, h0b1, h1b1, slots);

  void* args[] = { &Wih0, &Whh0, &bih0, &bhh0, &Wih1, &Whh1, &bih1, &bhh1,
                   &out, &xinit, &h0b0, &h0b1, &h1b0, &h1b1, &slots };
  hipLaunchCooperativeKernel((void*)lstm_persist, dim3(256), dim3(256),
                             args, SMEM_BYTES, stream);
}